// Round 1
// baseline (454.011 us; speedup 1.0000x reference)
//
#include <hip/hip_runtime.h>
#include <stdint.h>

// ---------- types ----------
typedef short bf16x8 __attribute__((ext_vector_type(8)));
typedef float f32x4  __attribute__((ext_vector_type(4)));

#define EPS_RMS 1.1920929e-07f
#define INV_SQRT_HD 0.08838834764831845f  // 1/sqrt(128)

// f32 -> bf16 bits, round-to-nearest-even
__device__ __forceinline__ short f2bf(float f) {
    uint32_t u = __float_as_uint(f);
    u += 0x7fffu + ((u >> 16) & 1u);
    return (short)(u >> 16);
}

using gld_t = const __attribute__((address_space(1))) unsigned int*;
using lds_t = __attribute__((address_space(3))) unsigned int*;

// async global->LDS, 16 bytes per lane (lane i lands at ldsbase + i*16)
__device__ __forceinline__ void glds16(const short* g, short* l) {
    __builtin_amdgcn_global_load_lds((gld_t)g, (lds_t)l, 16, 0, 0);
}

// ---------- kernel 1: f32 -> bf16 convert (vectorized x4) ----------
__global__ void cvt_f32_bf16(const float* __restrict__ in, short* __restrict__ out, int n) {
    int i = (blockIdx.x * blockDim.x + threadIdx.x) * 4;
    int stride = gridDim.x * blockDim.x * 4;
    for (; i < n; i += stride) {
        float4 v = *(const float4*)(in + i);
        short4 o;
        o.x = f2bf(v.x); o.y = f2bf(v.y); o.z = f2bf(v.z); o.w = f2bf(v.w);
        *(short4*)(out + i) = o;
    }
}

// ---------- kernel 2: C[M,N] = A[M,K] * Bw[N,K]^T  (bf16 in, f32 out) ----------
// m97 structure: 128x128 tile, BK=32, 4 waves (2x2), global_load_lds width 16.
__global__ __launch_bounds__(256, 1) void gemm_bt(
    const short* __restrict__ A, const short* __restrict__ Bw,
    float* __restrict__ C, int M, int N, int K)
{
    __shared__ short sA[128 * 32];
    __shared__ short sB[128 * 32];
    const int tid  = threadIdx.x;
    const int lane = tid & 63;
    const int wave = tid >> 6;
    const int wm = (wave >> 1) * 64;
    const int wn = (wave & 1) * 64;
    const size_t row0 = (size_t)blockIdx.y * 128;
    const size_t col0 = (size_t)blockIdx.x * 128;
    const int fr = lane & 15;        // fragment row (A) / col (B) / col (C)
    const int fk = (lane >> 4) * 8;  // fragment k offset

    f32x4 acc[4][4] = {};

    const short* gA = A + (row0 + (tid >> 2)) * (size_t)K + (tid & 3) * 8;
    const short* gB = Bw + (col0 + (tid >> 2)) * (size_t)K + (tid & 3) * 8;
    short* lA = sA + tid * 8;
    short* lB = sB + tid * 8;

    for (int k0 = 0; k0 < K; k0 += 32) {
        glds16(gA + k0, lA);
        glds16(gA + k0 + (size_t)64 * K, lA + 2048);
        glds16(gB + k0, lB);
        glds16(gB + k0 + (size_t)64 * K, lB + 2048);
        __syncthreads();   // drains vmcnt -> tiles ready

        bf16x8 af[4], bb[4];
        #pragma unroll
        for (int m = 0; m < 4; ++m)
            af[m] = *(const bf16x8*)(sA + (wm + m * 16 + fr) * 32 + fk);
        #pragma unroll
        for (int n = 0; n < 4; ++n)
            bb[n] = *(const bf16x8*)(sB + (wn + n * 16 + fr) * 32 + fk);
        #pragma unroll
        for (int m = 0; m < 4; ++m)
            #pragma unroll
            for (int n = 0; n < 4; ++n)
                acc[m][n] = __builtin_amdgcn_mfma_f32_16x16x32_bf16(af[m], bb[n], acc[m][n], 0, 0, 0);
        __syncthreads();   // protect LDS before next stage
    }

    const int cr = (lane >> 4) * 4;
    #pragma unroll
    for (int m = 0; m < 4; ++m)
        #pragma unroll
        for (int n = 0; n < 4; ++n)
            #pragma unroll
            for (int r = 0; r < 4; ++r)
                C[(row0 + wm + m * 16 + cr + r) * N + col0 + wn + n * 16 + fr] = acc[m][n][r];
}

// ---------- kernel 3: RoPE + RMSNorm for q,k; convert+transpose v ----------
// qkv: [B*L, 2304] f32 (q cols 0..2047, k 2048..2175, v 2176..2303)
// qbf: [B,H,L,128] bf16 (q scaled by 1/sqrt(hd)); kbf: [B,L,128]; vt: [B,128,L]
__global__ __launch_bounds__(256, 1) void prep_kernel(
    const float* __restrict__ qkv, const float* __restrict__ cosT,
    const float* __restrict__ sinT, short* __restrict__ qbf,
    short* __restrict__ kbf, short* __restrict__ vt)
{
    const int row  = blockIdx.x;      // b*2048 + l
    const int b    = row >> 11;
    const int l    = row & 2047;
    const int wave = threadIdx.x >> 6;
    const int lane = threadIdx.x & 63;
    const float* src = qkv + (size_t)row * 2304;
    const float c = cosT[l * 64 + lane];
    const float s = sinT[l * 64 + lane];

    for (int hh = wave; hh < 18; hh += 4) {
        if (hh < 17) {  // 0..15: q heads, 16: k
            const float* base = src + ((hh < 16) ? hh * 128 : 2048);
            float x1 = base[lane];
            float x2 = base[lane + 64];
            float y1 =  x1 * c + x2 * s;
            float y2 = -x1 * s + x2 * c;
            float ss = y1 * y1 + y2 * y2;
            #pragma unroll
            for (int m = 32; m >= 1; m >>= 1) ss += __shfl_xor(ss, m, 64);
            float sc = rsqrtf(ss * (1.0f / 128.0f) + EPS_RMS);
            if (hh < 16) {
                sc *= INV_SQRT_HD;  // fold attention scale into q
                short* dst = qbf + ((size_t)(b * 16 + hh) * 2048 + l) * 128;
                dst[lane]      = f2bf(y1 * sc);
                dst[lane + 64] = f2bf(y2 * sc);
            } else {
                short* dst = kbf + (size_t)row * 128;
                dst[lane]      = f2bf(y1 * sc);
                dst[lane + 64] = f2bf(y2 * sc);
            }
        } else {  // 17: v convert + transpose
            const float* base = src + 2176;
            short* dst = vt + (size_t)b * 128 * 2048 + l;
            dst[(size_t)lane * 2048]        = f2bf(base[lane]);
            dst[(size_t)(lane + 64) * 2048] = f2bf(base[lane + 64]);
        }
    }
}

// ---------- kernel 4: causal MQA flash attention ----------
// grid (B*H, L/64), 4 waves/block, each wave owns 16 q rows. KV blocks of 32.
// qbf [B,H,L,128] (pre-scaled), kbf [B,L,128], vt [B,128,L]; out obf [B,L,2048].
__global__ __launch_bounds__(256, 1) void attn_kernel(
    const short* __restrict__ qbf, const short* __restrict__ kbf,
    const short* __restrict__ vt, short* __restrict__ obf)
{
    __shared__ short p_lds[4][16 * 32];
    const int b    = blockIdx.x >> 4;
    const int h    = blockIdx.x & 15;
    const int wave = threadIdx.x >> 6;
    const int lane = threadIdx.x & 63;
    const int q0   = blockIdx.y * 64 + wave * 16;
    const int fr   = lane & 15;
    const int fk   = (lane >> 4) * 8;
    const short* qp = qbf + ((size_t)(b * 16 + h) * 2048 + q0) * 128;
    const short* kp = kbf + (size_t)b * 2048 * 128;
    const short* vp = vt  + (size_t)b * 128 * 2048;

    bf16x8 aq[4];
    #pragma unroll
    for (int c = 0; c < 4; ++c)
        aq[c] = *(const bf16x8*)(qp + fr * 128 + c * 32 + fk);

    float m_run[4], l_run[4];
    #pragma unroll
    for (int r = 0; r < 4; ++r) { m_run[r] = -3.0e38f; l_run[r] = 0.0f; }
    const f32x4 fz = {0.f, 0.f, 0.f, 0.f};
    f32x4 oacc[8];
    #pragma unroll
    for (int d = 0; d < 8; ++d) oacc[d] = fz;

    short* pl = p_lds[wave];
    const int qrow_base = q0 + (lane >> 4) * 4;

    for (int j0 = 0; j0 < q0 + 16; j0 += 32) {
        // S = q @ k^T  (two 16x16 tiles over kv cols j0..j0+31)
        f32x4 s0 = fz, s1 = fz;
        #pragma unroll
        for (int c = 0; c < 4; ++c) {
            bf16x8 bk = *(const bf16x8*)(kp + (size_t)(j0 + fr) * 128 + c * 32 + fk);
            s0 = __builtin_amdgcn_mfma_f32_16x16x32_bf16(aq[c], bk, s0, 0, 0, 0);
        }
        #pragma unroll
        for (int c = 0; c < 4; ++c) {
            bf16x8 bk = *(const bf16x8*)(kp + (size_t)(j0 + 16 + fr) * 128 + c * 32 + fk);
            s1 = __builtin_amdgcn_mfma_f32_16x16x32_bf16(aq[c], bk, s1, 0, 0, 0);
        }
        const int kv0 = j0 + fr, kv1 = j0 + 16 + fr;
        // online softmax per output row (reg r); row is spread over 16 lanes of the group
        #pragma unroll
        for (int r = 0; r < 4; ++r) {
            const int gq = qrow_base + r;
            float v0 = (kv0 <= gq) ? s0[r] : -3.0e38f;
            float v1 = (kv1 <= gq) ? s1[r] : -3.0e38f;
            float mx = fmaxf(v0, v1);
            #pragma unroll
            for (int mk = 8; mk >= 1; mk >>= 1) mx = fmaxf(mx, __shfl_xor(mx, mk, 64));
            const float mnew  = fmaxf(m_run[r], mx);
            const float alpha = __expf(m_run[r] - mnew);
            const float p0 = __expf(v0 - mnew);
            const float p1 = __expf(v1 - mnew);
            float rs = p0 + p1;
            #pragma unroll
            for (int mk = 8; mk >= 1; mk >>= 1) rs += __shfl_xor(rs, mk, 64);
            l_run[r] = l_run[r] * alpha + rs;
            m_run[r] = mnew;
            #pragma unroll
            for (int d = 0; d < 8; ++d) oacc[d][r] *= alpha;
            pl[((lane >> 4) * 4 + r) * 32 + fr]      = f2bf(p0);
            pl[((lane >> 4) * 4 + r) * 32 + 16 + fr] = f2bf(p1);
        }
        // P (C-layout) -> A-operand layout via LDS round trip (in-order per wave)
        bf16x8 pa = *(const bf16x8*)(pl + fr * 32 + fk);
        #pragma unroll
        for (int d = 0; d < 8; ++d) {
            bf16x8 bv = *(const bf16x8*)(vp + (size_t)(d * 16 + fr) * 2048 + j0 + fk);
            oacc[d] = __builtin_amdgcn_mfma_f32_16x16x32_bf16(pa, bv, oacc[d], 0, 0, 0);
        }
    }

    #pragma unroll
    for (int r = 0; r < 4; ++r) {
        const int gq = qrow_base + r;
        const float inv = 1.0f / l_run[r];
        short* orow = obf + ((size_t)b * 2048 + gq) * 2048 + h * 128;
        #pragma unroll
        for (int d = 0; d < 8; ++d)
            orow[d * 16 + fr] = f2bf(oacc[d][r] * inv);
    }
}

// ---------- launch ----------
extern "C" void kernel_launch(void* const* d_in, const int* in_sizes, int n_in,
                              void* d_out, int out_size, void* d_ws, size_t ws_size,
                              hipStream_t stream)
{
    const float* x    = (const float*)d_in[0];
    const float* cosT = (const float*)d_in[1];
    const float* sinT = (const float*)d_in[2];
    const float* wq   = (const float*)d_in[3];
    const float* wk   = (const float*)d_in[4];
    const float* wv   = (const float*)d_in[5];
    const float* wo   = (const float*)d_in[6];
    float* out = (float*)d_out;

    char* ws = (char*)d_ws;
    size_t off = 0;
    auto alloc = [&](size_t bytes) {
        char* p = ws + off;
        off = (off + bytes + 255) & ~(size_t)255;
        return p;
    };
    short* x_bf  = (short*)alloc((size_t)4096 * 2048 * 2);   // also reused as attn_bf
    short* wcat  = (short*)alloc((size_t)2304 * 2048 * 2);   // [wq;wk;wv]
    short* wo_bf = (short*)alloc((size_t)2048 * 2048 * 2);
    float* qkv   = (float*)alloc((size_t)4096 * 2304 * 4);
    short* q_bf  = (short*)alloc((size_t)2 * 16 * 2048 * 128 * 2);
    short* k_bf  = (short*)alloc((size_t)2 * 2048 * 128 * 2);
    short* v_t   = (short*)alloc((size_t)2 * 128 * 2048 * 2);
    short* attn_bf = x_bf;  // x_bf dead after GEMM1; alias to save workspace
    (void)in_sizes; (void)n_in; (void)out_size; (void)ws_size;

    cvt_f32_bf16<<<1024, 256, 0, stream>>>(x, x_bf, 4096 * 2048);
    cvt_f32_bf16<<<512, 256, 0, stream>>>(wq, wcat, 2048 * 2048);
    cvt_f32_bf16<<<64, 256, 0, stream>>>(wk, wcat + (size_t)2048 * 2048, 128 * 2048);
    cvt_f32_bf16<<<64, 256, 0, stream>>>(wv, wcat + (size_t)2176 * 2048, 128 * 2048);
    cvt_f32_bf16<<<512, 256, 0, stream>>>(wo, wo_bf, 2048 * 2048);

    // qkv = x @ [wq;wk;wv]^T   (M=4096, N=2304, K=2048)
    gemm_bt<<<dim3(18, 32), 256, 0, stream>>>(x_bf, wcat, qkv, 4096, 2304, 2048);

    prep_kernel<<<4096, 256, 0, stream>>>(qkv, cosT, sinT, q_bf, k_bf, v_t);

    attn_kernel<<<dim3(32, 32), 256, 0, stream>>>(q_bf, k_bf, v_t, attn_bf);

    // out = attn @ wo^T   (M=4096, N=2048, K=2048)
    gemm_bt<<<dim3(16, 32), 256, 0, stream>>>(attn_bf, wo_bf, out, 4096, 2048, 2048);
}

// Round 4
// 324.604 us; speedup vs baseline: 1.3987x; 1.3987x over previous
//
#include <hip/hip_runtime.h>
#include <stdint.h>

// ---------- types ----------
typedef short bf16x8 __attribute__((ext_vector_type(8)));
typedef float f32x4  __attribute__((ext_vector_type(4)));
typedef float f32x16 __attribute__((ext_vector_type(16)));

#define EPS_RMS 1.1920929e-07f
#define INV_SQRT_HD 0.08838834764831845f  // 1/sqrt(128)
#define NEGBIG (-3.0e38f)

// f32 -> bf16 bits, round-to-nearest-even
__device__ __forceinline__ short f2bf(float f) {
    uint32_t u = __float_as_uint(f);
    u += 0x7fffu + ((u >> 16) & 1u);
    return (short)(u >> 16);
}

__device__ __forceinline__ unsigned int pack2(float lo, float hi) {
    return (unsigned int)(unsigned short)f2bf(lo) |
           ((unsigned int)(unsigned short)f2bf(hi) << 16);
}

using gld_t = const __attribute__((address_space(1))) unsigned int*;
using lds_t = __attribute__((address_space(3))) unsigned int*;

// async global->LDS, 16 bytes per lane (lane i lands at ldsbase + i*16)
__device__ __forceinline__ void glds16(const short* g, short* l) {
    __builtin_amdgcn_global_load_lds((gld_t)g, (lds_t)l, 16, 0, 0);
}

// ---------- kernel 1: f32 -> bf16 convert (vectorized x4) ----------
__global__ void cvt_f32_bf16(const float* __restrict__ in, short* __restrict__ out, int n) {
    int i = (blockIdx.x * blockDim.x + threadIdx.x) * 4;
    int stride = gridDim.x * blockDim.x * 4;
    for (; i < n; i += stride) {
        float4 v = *(const float4*)(in + i);
        short4 o;
        o.x = f2bf(v.x); o.y = f2bf(v.y); o.z = f2bf(v.z); o.w = f2bf(v.w);
        *(short4*)(out + i) = o;
    }
}

// ---------- kernel 2: C[M,N] = A[M,K] * Bw[N,K]^T  (bf16 in, f32 out) ----------
__global__ __launch_bounds__(256, 1) void gemm_bt(
    const short* __restrict__ A, const short* __restrict__ Bw,
    float* __restrict__ C, int M, int N, int K)
{
    __shared__ short sA[128 * 32];
    __shared__ short sB[128 * 32];
    const int tid  = threadIdx.x;
    const int lane = tid & 63;
    const int wave = tid >> 6;
    const int wm = (wave >> 1) * 64;
    const int wn = (wave & 1) * 64;
    const size_t row0 = (size_t)blockIdx.y * 128;
    const size_t col0 = (size_t)blockIdx.x * 128;
    const int fr = lane & 15;
    const int fk = (lane >> 4) * 8;

    f32x4 acc[4][4] = {};

    const short* gA = A + (row0 + (tid >> 2)) * (size_t)K + (tid & 3) * 8;
    const short* gB = Bw + (col0 + (tid >> 2)) * (size_t)K + (tid & 3) * 8;
    short* lA = sA + tid * 8;
    short* lB = sB + tid * 8;

    for (int k0 = 0; k0 < K; k0 += 32) {
        glds16(gA + k0, lA);
        glds16(gA + k0 + (size_t)64 * K, lA + 2048);
        glds16(gB + k0, lB);
        glds16(gB + k0 + (size_t)64 * K, lB + 2048);
        __syncthreads();

        bf16x8 af[4], bb[4];
        #pragma unroll
        for (int m = 0; m < 4; ++m)
            af[m] = *(const bf16x8*)(sA + (wm + m * 16 + fr) * 32 + fk);
        #pragma unroll
        for (int n = 0; n < 4; ++n)
            bb[n] = *(const bf16x8*)(sB + (wn + n * 16 + fr) * 32 + fk);
        #pragma unroll
        for (int m = 0; m < 4; ++m)
            #pragma unroll
            for (int n = 0; n < 4; ++n)
                acc[m][n] = __builtin_amdgcn_mfma_f32_16x16x32_bf16(af[m], bb[n], acc[m][n], 0, 0, 0);
        __syncthreads();
    }

    const int cr = (lane >> 4) * 4;
    #pragma unroll
    for (int m = 0; m < 4; ++m)
        #pragma unroll
        for (int n = 0; n < 4; ++n)
            #pragma unroll
            for (int r = 0; r < 4; ++r)
                C[(row0 + wm + m * 16 + cr + r) * N + col0 + wn + n * 16 + fr] = acc[m][n][r];
}

// ---------- kernel 3: RoPE + RMSNorm for q,k; convert+transpose v ----------
__global__ __launch_bounds__(256, 1) void prep_kernel(
    const float* __restrict__ qkv, const float* __restrict__ cosT,
    const float* __restrict__ sinT, short* __restrict__ qbf,
    short* __restrict__ kbf, short* __restrict__ vt)
{
    const int row  = blockIdx.x;      // b*2048 + l
    const int b    = row >> 11;
    const int l    = row & 2047;
    const int wave = threadIdx.x >> 6;
    const int lane = threadIdx.x & 63;
    const float* src = qkv + (size_t)row * 2304;
    const float c = cosT[l * 64 + lane];
    const float s = sinT[l * 64 + lane];

    for (int hh = wave; hh < 18; hh += 4) {
        if (hh < 17) {
            const float* base = src + ((hh < 16) ? hh * 128 : 2048);
            float x1 = base[lane];
            float x2 = base[lane + 64];
            float y1 =  x1 * c + x2 * s;
            float y2 = -x1 * s + x2 * c;
            float ss = y1 * y1 + y2 * y2;
            #pragma unroll
            for (int m = 32; m >= 1; m >>= 1) ss += __shfl_xor(ss, m, 64);
            float sc = rsqrtf(ss * (1.0f / 128.0f) + EPS_RMS);
            if (hh < 16) {
                sc *= INV_SQRT_HD;
                short* dst = qbf + ((size_t)(b * 16 + hh) * 2048 + l) * 128;
                dst[lane]      = f2bf(y1 * sc);
                dst[lane + 64] = f2bf(y2 * sc);
            } else {
                short* dst = kbf + (size_t)row * 128;
                dst[lane]      = f2bf(y1 * sc);
                dst[lane + 64] = f2bf(y2 * sc);
            }
        } else {
            const float* base = src + 2176;
            short* dst = vt + (size_t)b * 128 * 2048 + l;
            dst[(size_t)lane * 2048]        = f2bf(base[lane]);
            dst[(size_t)(lane + 64) * 2048] = f2bf(base[lane + 64]);
        }
    }
}

// ---------- kernel 4: causal MQA flash attention, 32x32 swapped-QK^T ----------
// Each wave owns 32 q rows; S^T = mfma(K, Q^T) puts a full P-row in one lane
// (col = lane&31 = q). O^T = mfma(V^T, P^T) keeps lane<->q ownership so the
// online-softmax rescale is lane-local. KVBLK=64, K/V read straight from L2.
// Wave q-tiles {j, 31-j, 32+j, 63-j} -> constant per-block causal work.
__global__ __launch_bounds__(256, 2) void attn_kernel(
    const short* __restrict__ qbf, const short* __restrict__ kbf,
    const short* __restrict__ vt, short* __restrict__ obf)
{
    __shared__ short o_sh[4][32][136];  // +8 pad: conflict-free epilogue
    const int tid  = threadIdx.x;
    const int wave = tid >> 6;
    const int lane = tid & 63;
    const int l31  = lane & 31;
    const int hi   = lane >> 5;

    const int gh = blockIdx.x & 31;
    const int b  = gh >> 4;
    const int h  = gh & 15;
    const int i0 = blockIdx.x >> 5;            // 0..15
    const int j  = (i0 < 8) ? i0 : 23 - i0;    // pairing perm (dispatch-order balance)
    int tile;
    switch (wave) {
        case 0:  tile = j;      break;
        case 1:  tile = 31 - j; break;
        case 2:  tile = 32 + j; break;
        default: tile = 63 - j; break;
    }
    const int q0 = tile * 32;
    const int gq = q0 + l31;                   // this lane's q row

    const short* qp = qbf + ((size_t)(b * 16 + h) * 2048 + gq) * 128 + hi * 8;
    const short* kp = kbf + (size_t)b * 2048 * 128 + hi * 8;
    const short* vp = vt  + (size_t)b * 128 * 2048 + hi * 8;

    // Q fragments: B-operand of S^T (col = q). 8 k-slots of 16 over hd=128.
    bf16x8 qf[8];
    #pragma unroll
    for (int s = 0; s < 8; ++s) qf[s] = *(const bf16x8*)(qp + s * 16);

    f32x16 oacc[4];
    #pragma unroll
    for (int dt = 0; dt < 4; ++dt)
        #pragma unroll
        for (int r = 0; r < 16; ++r) oacc[dt][r] = 0.f;
    float m_run = 0.f, lsum = 0.f;

    for (int j0 = 0; j0 < q0 + 32; j0 += 64) {
        const bool haveT1 = (j0 + 32) <= (q0 + 31);

        // ---- S^T = K · Q^T : two 32-kv tiles ----
        f32x16 s0a, s1a;
        #pragma unroll
        for (int r = 0; r < 16; ++r) { s0a[r] = 0.f; s1a[r] = NEGBIG; }

        const short* krow0 = kp + (size_t)(j0 + l31) * 128;
        #pragma unroll
        for (int s = 0; s < 8; ++s) {
            bf16x8 kf = *(const bf16x8*)(krow0 + s * 16);
            s0a = __builtin_amdgcn_mfma_f32_32x32x16_bf16(kf, qf[s], s0a, 0, 0, 0);
        }
        if (haveT1) {
            #pragma unroll
            for (int r = 0; r < 16; ++r) s1a[r] = 0.f;
            const short* krow1 = kp + (size_t)(j0 + 32 + l31) * 128;
            #pragma unroll
            for (int s = 0; s < 8; ++s) {
                bf16x8 kf = *(const bf16x8*)(krow1 + s * 16);
                s1a = __builtin_amdgcn_mfma_f32_32x32x16_bf16(kf, qf[s], s1a, 0, 0, 0);
            }
        }

        // ---- causal mask (diagonal tile only) ----
        if (j0 + 63 > q0) {
            #pragma unroll
            for (int r = 0; r < 16; ++r) {
                const int base = (r & 3) + 8 * (r >> 2) + 4 * hi;
                if (j0 + base > gq) s0a[r] = NEGBIG;
                if (haveT1 && (j0 + 32 + base > gq)) s1a[r] = NEGBIG;
            }
        }

        // ---- row max (in-register tree + one cross-half shuffle) ----
        float t8[8];
        #pragma unroll
        for (int r = 0; r < 8; ++r)
            t8[r] = fmaxf(fmaxf(s0a[r], s0a[r + 8]), fmaxf(s1a[r], s1a[r + 8]));
        #pragma unroll
        for (int r = 0; r < 4; ++r) t8[r] = fmaxf(t8[r], t8[r + 4]);
        float pmax = fmaxf(fmaxf(t8[0], t8[1]), fmaxf(t8[2], t8[3]));
        pmax = fmaxf(pmax, __shfl_xor(pmax, 32));

        // ---- defer-max rescale (T13, THR=8) ----
        if (!__all(pmax <= m_run + 8.0f)) {
            const float mnew  = fmaxf(m_run, pmax);
            const float alpha = __expf(m_run - mnew);
            #pragma unroll
            for (int dt = 0; dt < 4; ++dt)
                #pragma unroll
                for (int r = 0; r < 16; ++r) oacc[dt][r] *= alpha;
            lsum *= alpha;
            m_run = mnew;
        }

        // ---- P = exp(S - m), row sum ----
        float rs = 0.f;
        #pragma unroll
        for (int r = 0; r < 16; ++r) {
            s0a[r] = __expf(s0a[r] - m_run);
            s1a[r] = __expf(s1a[r] - m_run);
        }
        {
            float a8[8];
            #pragma unroll
            for (int r = 0; r < 8; ++r)
                a8[r] = (s0a[r] + s0a[r + 8]) + (s1a[r] + s1a[r + 8]);
            #pragma unroll
            for (int r = 0; r < 4; ++r) a8[r] += a8[r + 4];
            rs = (a8[0] + a8[1]) + (a8[2] + a8[3]);
        }
        rs += __shfl_xor(rs, 32);
        lsum += rs;

        // ---- P^T -> B-operand frags: pack pairs + exchange halves ----
        union FragU { unsigned int u[4]; bf16x8 v; };
        unsigned int W[8], X[8];
        #pragma unroll
        for (int jw = 0; jw < 8; ++jw) {
            W[jw] = pack2(s0a[2 * jw], s0a[2 * jw + 1]);
            X[jw] = (unsigned int)__shfl_xor((int)W[jw], 32);
        }
        FragU f0, f1;
        if (hi) {
            f0.u[0] = X[2]; f0.u[1] = X[3]; f0.u[2] = W[2]; f0.u[3] = W[3];
            f1.u[0] = X[6]; f1.u[1] = X[7]; f1.u[2] = W[6]; f1.u[3] = W[7];
        } else {
            f0.u[0] = W[0]; f0.u[1] = W[1]; f0.u[2] = X[0]; f0.u[3] = X[1];
            f1.u[0] = W[4]; f1.u[1] = W[5]; f1.u[2] = X[4]; f1.u[3] = X[5];
        }

        // ---- O^T += V^T · P^T  (slots 0,1 = kv j0..j0+31) ----
        #pragma unroll
        for (int dt = 0; dt < 4; ++dt) {
            const short* vrow = vp + (size_t)(dt * 32 + l31) * 2048 + j0;
            bf16x8 vf0 = *(const bf16x8*)(vrow);
            bf16x8 vf1 = *(const bf16x8*)(vrow + 16);
            oacc[dt] = __builtin_amdgcn_mfma_f32_32x32x16_bf16(vf0, f0.v, oacc[dt], 0, 0, 0);
            oacc[dt] = __builtin_amdgcn_mfma_f32_32x32x16_bf16(vf1, f1.v, oacc[dt], 0, 0, 0);
        }

        if (haveT1) {
            unsigned int W1[8], X1[8];
            #pragma unroll
            for (int jw = 0; jw < 8; ++jw) {
                W1[jw] = pack2(s1a[2 * jw], s1a[2 * jw + 1]);
                X1[jw] = (unsigned int)__shfl_xor((int)W1[jw], 32);
            }
            FragU f2, f3;
            if (hi) {
                f2.u[0] = X1[2]; f2.u[1] = X1[3]; f2.u[2] = W1[2]; f2.u[3] = W1[3];
                f3.u[0] = X1[6]; f3.u[1] = X1[7]; f3.u[2] = W1[6]; f3.u[3] = W1[7];
            } else {
                f2.u[0] = W1[0]; f2.u[1] = W1[1]; f2.u[2] = X1[0]; f2.u[3] = X1[1];
                f3.u[0] = W1[4]; f3.u[1] = W1[5]; f3.u[2] = X1[4]; f3.u[3] = X1[5];
            }
            #pragma unroll
            for (int dt = 0; dt < 4; ++dt) {
                const short* vrow = vp + (size_t)(dt * 32 + l31) * 2048 + j0;
                bf16x8 vf2 = *(const bf16x8*)(vrow + 32);
                bf16x8 vf3 = *(const bf16x8*)(vrow + 48);
                oacc[dt] = __builtin_amdgcn_mfma_f32_32x32x16_bf16(vf2, f2.v, oacc[dt], 0, 0, 0);
                oacc[dt] = __builtin_amdgcn_mfma_f32_32x32x16_bf16(vf3, f3.v, oacc[dt], 0, 0, 0);
            }
        }
    }

    // ---- epilogue: normalize, transpose via LDS, coalesced store ----
    const float inv = 1.0f / lsum;
    #pragma unroll
    for (int dt = 0; dt < 4; ++dt)
        #pragma unroll
        for (int r = 0; r < 16; ++r) {
            const int d = dt * 32 + (r & 3) + 8 * (r >> 2) + 4 * hi;
            o_sh[wave][l31][d] = f2bf(oacc[dt][r] * inv);
        }
    __syncthreads();
    const int rlane = lane >> 4;       // 0..3
    const int dl = (lane & 15) * 8;
    #pragma unroll
    for (int pass = 0; pass < 8; ++pass) {
        const int row = pass * 4 + rlane;
        bf16x8 ov = *(const bf16x8*)(&o_sh[wave][row][dl]);
        *(bf16x8*)(obf + ((size_t)b * 2048 + q0 + row) * 2048 + h * 128 + dl) = ov;
    }
}

// ---------- launch ----------
extern "C" void kernel_launch(void* const* d_in, const int* in_sizes, int n_in,
                              void* d_out, int out_size, void* d_ws, size_t ws_size,
                              hipStream_t stream)
{
    const float* x    = (const float*)d_in[0];
    const float* cosT = (const float*)d_in[1];
    const float* sinT = (const float*)d_in[2];
    const float* wq   = (const float*)d_in[3];
    const float* wk   = (const float*)d_in[4];
    const float* wv   = (const float*)d_in[5];
    const float* wo   = (const float*)d_in[6];
    float* out = (float*)d_out;

    char* ws = (char*)d_ws;
    size_t off = 0;
    auto alloc = [&](size_t bytes) {
        char* p = ws + off;
        off = (off + bytes + 255) & ~(size_t)255;
        return p;
    };
    short* x_bf  = (short*)alloc((size_t)4096 * 2048 * 2);   // also reused as attn_bf
    short* wcat  = (short*)alloc((size_t)2304 * 2048 * 2);   // [wq;wk;wv]
    short* wo_bf = (short*)alloc((size_t)2048 * 2048 * 2);
    float* qkv   = (float*)alloc((size_t)4096 * 2304 * 4);
    short* q_bf  = (short*)alloc((size_t)2 * 16 * 2048 * 128 * 2);
    short* k_bf  = (short*)alloc((size_t)2 * 2048 * 128 * 2);
    short* v_t   = (short*)alloc((size_t)2 * 128 * 2048 * 2);
    short* attn_bf = x_bf;  // x_bf dead after GEMM1; alias to save workspace
    (void)in_sizes; (void)n_in; (void)out_size; (void)ws_size;

    cvt_f32_bf16<<<1024, 256, 0, stream>>>(x, x_bf, 4096 * 2048);
    cvt_f32_bf16<<<512, 256, 0, stream>>>(wq, wcat, 2048 * 2048);
    cvt_f32_bf16<<<64, 256, 0, stream>>>(wk, wcat + (size_t)2048 * 2048, 128 * 2048);
    cvt_f32_bf16<<<64, 256, 0, stream>>>(wv, wcat + (size_t)2176 * 2048, 128 * 2048);
    cvt_f32_bf16<<<512, 256, 0, stream>>>(wo, wo_bf, 2048 * 2048);

    // qkv = x @ [wq;wk;wv]^T   (M=4096, N=2304, K=2048)
    gemm_bt<<<dim3(18, 32), 256, 0, stream>>>(x_bf, wcat, qkv, 4096, 2304, 2048);

    prep_kernel<<<4096, 256, 0, stream>>>(qkv, cosT, sinT, q_bf, k_bf, v_t);

    attn_kernel<<<512, 256, 0, stream>>>(q_bf, k_bf, v_t, attn_bf);

    // out = attn @ wo^T   (M=4096, N=2048, K=2048)
    gemm_bt<<<dim3(16, 32), 256, 0, stream>>>(attn_bf, wo_bf, out, 4096, 2048, 2048);
}